// Round 1
// baseline (729.173 us; speedup 1.0000x reference)
//
#include <hip/hip_runtime.h>
#include <cstdint>
#include <cstddef>

#define E_ 32
#define TOPK_ 4
#define H_ 1024
#define I_ 1024
#define T_ 2048
#define ALPHA_ 1.702f
#define LIMIT_ 7.0f
#define BK_ 32
#define BKP_ 40   // padded LDS row (bf16): 80 B -> 2-way bank alias = free
#define TP_ 66    // transpose LDS pad (elems): 132 B stride -> bank-friendly

typedef __attribute__((ext_vector_type(8))) short s8;
typedef __attribute__((ext_vector_type(4))) float f4;

__device__ __forceinline__ unsigned short f2bf(float f) {
  unsigned int u = __float_as_uint(f);
  return (unsigned short)((u + 0x7fffu + ((u >> 16) & 1u)) >> 16);
}

// ---------------------------------------------------------------------------
// Kernel 0a: x fp32 -> bf16 streaming cast.
// ---------------------------------------------------------------------------
__global__ __launch_bounds__(256)
void cast_x_kernel(const float* __restrict__ x, unsigned short* __restrict__ xb) {
  size_t i = (size_t)(blockIdx.x * 256 + threadIdx.x) * 8;
  float4 a = *(const float4*)(x + i);
  float4 b = *(const float4*)(x + i + 4);
  s8 v;
  v[0] = (short)f2bf(a.x); v[1] = (short)f2bf(a.y);
  v[2] = (short)f2bf(a.z); v[3] = (short)f2bf(a.w);
  v[4] = (short)f2bf(b.x); v[5] = (short)f2bf(b.y);
  v[6] = (short)f2bf(b.z); v[7] = (short)f2bf(b.w);
  *(s8*)(xb + i) = v;
}

// ---------------------------------------------------------------------------
// Kernel 0b: weight transpose + cast (+ optional gate/up deinterleave).
// src: [E][src_rows][src_cols] fp32, contiguous in cols.
// deint=0: dst[e][c][r] = bf16(src[e][r][c])            (dst [E][C][R])
// deint=1: dst[e][c&1][c>>1][r] = bf16(src[e][r][c])    (dst [E][2][C/2][R])
// 64x64 tiles; coalesced fp32 reads, coalesced b128 bf16 writes.
// ---------------------------------------------------------------------------
__global__ __launch_bounds__(256)
void transpose_cast(const float* __restrict__ src, unsigned short* __restrict__ dst,
                    int src_rows, int src_cols, int deint) {
  int e = blockIdx.z;
  int c0 = blockIdx.x * 64;
  int r0 = blockIdx.y * 64;
  int tid = threadIdx.x;
  __shared__ unsigned short ldsT[64][TP_];   // ldsT[c][r]

  const float* sp = src + (size_t)e * src_rows * src_cols
                        + (size_t)r0 * src_cols + c0;
  int r = tid >> 2, cq = tid & 3;
  const float* rowp = sp + (size_t)r * src_cols + cq * 4;
  #pragma unroll
  for (int j = 0; j < 4; ++j) {
    float4 v = *(const float4*)(rowp + j * 16);
    int c = cq * 4 + j * 16;
    ldsT[c + 0][r] = f2bf(v.x);
    ldsT[c + 1][r] = f2bf(v.y);
    ldsT[c + 2][r] = f2bf(v.z);
    ldsT[c + 3][r] = f2bf(v.w);
  }
  __syncthreads();

  int co = tid >> 2, hq = tid & 3;
  s8 v0 = *(s8*)&ldsT[co][hq * 16];
  s8 v1 = *(s8*)&ldsT[co][hq * 16 + 8];
  int C = c0 + co;
  size_t out_off;
  if (deint) {
    out_off = (size_t)e * src_cols * src_rows
            + (size_t)(C & 1) * (src_cols >> 1) * src_rows
            + (size_t)(C >> 1) * src_rows + r0 + hq * 16;
  } else {
    out_off = (size_t)e * src_cols * src_rows
            + (size_t)C * src_rows + r0 + hq * 16;
  }
  *(s8*)(dst + out_off) = v0;
  *(s8*)(dst + out_off + 8) = v1;
}

// ---------------------------------------------------------------------------
// Kernel 1: router (float4 loads; otherwise unchanged).
// ---------------------------------------------------------------------------
__global__ __launch_bounds__(128)
void router_kernel(const float* __restrict__ x,
                   const float* __restrict__ rw,
                   const float* __restrict__ rb,
                   float* __restrict__ scores,
                   int* __restrict__ counts,
                   int* __restrict__ tok_list,
                   float* __restrict__ w_list) {
  int t = blockIdx.x;
  int tid = threadIdx.x;
  __shared__ float partial[128];
  __shared__ float logits[E_];
  int e = tid & 31, q = tid >> 5;
  const float4* xp = (const float4*)(x + (size_t)t * H_ + q * 256);
  const float4* wp = (const float4*)(rw + (size_t)e * H_ + q * 256);
  float s = 0.f;
  #pragma unroll 8
  for (int h = 0; h < 64; ++h) {
    float4 a = xp[h], b = wp[h];
    s += a.x * b.x + a.y * b.y + a.z * b.z + a.w * b.w;
  }
  partial[tid] = s;
  __syncthreads();
  if (tid < 32)
    logits[tid] = partial[tid] + partial[tid + 32] + partial[tid + 64] +
                  partial[tid + 96] + rb[tid];
  __syncthreads();
  if (tid == 0) {
    float l[E_];
    #pragma unroll
    for (int i = 0; i < E_; ++i) l[i] = logits[i];
    int idx[TOPK_]; float v[TOPK_];
    for (int k = 0; k < TOPK_; ++k) {
      int bi = 0; float bv = -1e30f;
      for (int i = 0; i < E_; ++i)
        if (l[i] > bv) { bv = l[i]; bi = i; }
      idx[k] = bi; v[k] = bv; l[bi] = -1e30f;
    }
    float m = v[0], den = 0.f, w[TOPK_];
    for (int k = 0; k < TOPK_; ++k) { w[k] = expf(v[k] - m); den += w[k]; }
    float inv = 1.f / den;
    float* srow = scores + (size_t)t * E_;
    #pragma unroll
    for (int i = 0; i < E_; ++i) srow[i] = 0.f;
    for (int k = 0; k < TOPK_; ++k) {
      float wk = w[k] * inv;
      srow[idx[k]] = wk;
      int pos = atomicAdd(&counts[idx[k]], 1);
      tok_list[idx[k] * T_ + pos] = t * TOPK_ + k;
      w_list[idx[k] * T_ + pos] = wk;
    }
  }
}

// ---------------------------------------------------------------------------
// Kernel 2: gate_up, bf16 MFMA. Weights pre-cast/transposed: wgu [E][2][I][H]
// bf16 (k-contiguous). Staging is now pure b128 load + ds_write_b128, no
// conversions. Double-buffered LDS, register prefetch, 1 barrier / chunk.
// ---------------------------------------------------------------------------
__global__ __launch_bounds__(256)
void gateup_mfma(const unsigned short* __restrict__ xb,   // [T][H] bf16
                 const unsigned short* __restrict__ wgu,  // [E][2][I][H] bf16
                 const float* __restrict__ gb,            // [E][2I]
                 const int* __restrict__ counts,
                 const int* __restrict__ tok_list,
                 unsigned short* __restrict__ act) {      // [T*4][I] bf16
  int e = blockIdx.z;
  int cnt = counts[e];
  int t0 = blockIdx.y * 64;
  if (t0 >= cnt) return;
  int itile = blockIdx.x;
  int tid = threadIdx.x;
  int lane = tid & 63;
  int wave = tid >> 6;
  int wm = wave >> 1, wn = wave & 1;

  __shared__ __align__(16) unsigned short Xs[2][64][BKP_];
  __shared__ __align__(16) unsigned short Wg[2][128][BKP_];
  __shared__ int toks[64];

  if (tid < 64) {
    int slot = t0 + tid;
    toks[tid] = (slot < cnt) ? tok_list[e * T_ + slot] : -1;
  }
  __syncthreads();

  f4 accg[2][2] = {};
  f4 accu[2][2] = {};

  int row = tid >> 2, q = tid & 3;
  int aenc = toks[row];
  const unsigned short* axp = xb + (size_t)(aenc >> 2) * H_ + q * 8;
  const unsigned short* bp0 = wgu + (size_t)e * 2 * I_ * H_
                            + (size_t)(itile * 64 + row) * H_ + q * 8;   // gate
  const unsigned short* bp1 = bp0 + (size_t)I_ * H_;                     // up

  int fm = lane & 15, ko = (lane >> 4) * 8;

  s8 pA = {};
  s8 pB0, pB1;
  if (aenc >= 0) pA = *(const s8*)axp;
  pB0 = *(const s8*)bp0;
  pB1 = *(const s8*)bp1;

  int buf = 0;
  for (int c = 0; c < H_ / BK_; ++c) {
    *(s8*)&Xs[buf][row][q * 8] = pA;
    *(s8*)&Wg[buf][row][q * 8] = pB0;
    *(s8*)&Wg[buf][64 + row][q * 8] = pB1;
    __syncthreads();
    if (c + 1 < H_ / BK_) {
      int k0 = (c + 1) * BK_;
      if (aenc >= 0) pA = *(const s8*)(axp + k0);
      pB0 = *(const s8*)(bp0 + k0);
      pB1 = *(const s8*)(bp1 + k0);
    }
    {
      s8 a0 = *(s8*)&Xs[buf][wm * 32 + fm][ko];
      s8 a1 = *(s8*)&Xs[buf][wm * 32 + 16 + fm][ko];
      #pragma unroll
      for (int g = 0; g < 2; ++g) {
        s8 bg = *(s8*)&Wg[buf][wn * 32 + g * 16 + fm][ko];
        s8 bu = *(s8*)&Wg[buf][64 + wn * 32 + g * 16 + fm][ko];
        accg[0][g] = __builtin_amdgcn_mfma_f32_16x16x32_bf16(a0, bg, accg[0][g], 0, 0, 0);
        accg[1][g] = __builtin_amdgcn_mfma_f32_16x16x32_bf16(a1, bg, accg[1][g], 0, 0, 0);
        accu[0][g] = __builtin_amdgcn_mfma_f32_16x16x32_bf16(a0, bu, accu[0][g], 0, 0, 0);
        accu[1][g] = __builtin_amdgcn_mfma_f32_16x16x32_bf16(a1, bu, accu[1][g], 0, 0, 0);
      }
    }
    buf ^= 1;
  }

  int rq = lane >> 4;
  #pragma unroll
  for (int g = 0; g < 2; ++g) {
    int i = itile * 64 + wn * 32 + g * 16 + (lane & 15);
    float bg_ = gb[e * 2 * I_ + 2 * i];
    float bu_ = gb[e * 2 * I_ + 2 * i + 1];
    #pragma unroll
    for (int f = 0; f < 2; ++f) {
      #pragma unroll
      for (int r = 0; r < 4; ++r) {
        int m = wm * 32 + f * 16 + rq * 4 + r;
        int enc = toks[m];
        if (enc < 0) continue;
        float gv = accg[f][g][r] + bg_;
        float uv = accu[f][g][r] + bu_;
        gv = fminf(gv, LIMIT_);
        uv = fminf(fmaxf(uv, -LIMIT_), LIMIT_);
        float glu = gv / (1.f + __expf(-ALPHA_ * gv));
        act[(size_t)enc * I_ + i] = f2bf((uv + 1.f) * glu);
      }
    }
  }
}

// ---------------------------------------------------------------------------
// Kernel 3: down-proj, bf16 MFMA. Weights pre-cast/transposed: wdt [E][H][I]
// bf16 (k-contiguous). Same clean staging.
// ---------------------------------------------------------------------------
__global__ __launch_bounds__(256)
void down_mfma(const unsigned short* __restrict__ act,  // [T*4][I] bf16
               const unsigned short* __restrict__ wdt,  // [E][H][I] bf16
               const float* __restrict__ db,            // [E][H]
               const int* __restrict__ counts,
               const int* __restrict__ tok_list,
               const float* __restrict__ w_list,
               float* __restrict__ dsout) {             // [T*4][H] fp32
  int e = blockIdx.z;
  int cnt = counts[e];
  int t0 = blockIdx.y * 64;
  if (t0 >= cnt) return;
  int htile = blockIdx.x;
  int tid = threadIdx.x;
  int lane = tid & 63;
  int wave = tid >> 6;
  int wm = wave >> 1, wn = wave & 1;

  __shared__ __align__(16) unsigned short Xs[2][64][BKP_];
  __shared__ __align__(16) unsigned short Wd[2][128][BKP_];
  __shared__ int toks[64];
  __shared__ float tws[64];

  if (tid < 64) {
    int slot = t0 + tid;
    bool ok = slot < cnt;
    toks[tid] = ok ? tok_list[e * T_ + slot] : -1;
    tws[tid]  = ok ? w_list[e * T_ + slot] : 0.f;
  }
  __syncthreads();

  f4 acc[2][4] = {};

  int row = tid >> 2, q = tid & 3;
  int aenc = toks[row];
  const unsigned short* axp = act + (size_t)aenc * I_ + q * 8;
  const unsigned short* bp0 = wdt + (size_t)e * H_ * I_
                            + (size_t)(htile * 128 + row) * I_ + q * 8;
  const unsigned short* bp1 = bp0 + (size_t)64 * I_;

  int fm = lane & 15, ko = (lane >> 4) * 8;

  s8 pA = {};
  s8 pB0, pB1;
  if (aenc >= 0) pA = *(const s8*)axp;
  pB0 = *(const s8*)bp0;
  pB1 = *(const s8*)bp1;

  int buf = 0;
  for (int c = 0; c < I_ / BK_; ++c) {
    *(s8*)&Xs[buf][row][q * 8] = pA;
    *(s8*)&Wd[buf][row][q * 8] = pB0;
    *(s8*)&Wd[buf][64 + row][q * 8] = pB1;
    __syncthreads();
    if (c + 1 < I_ / BK_) {
      int k0 = (c + 1) * BK_;
      if (aenc >= 0) pA = *(const s8*)(axp + k0);
      pB0 = *(const s8*)(bp0 + k0);
      pB1 = *(const s8*)(bp1 + k0);
    }
    {
      s8 a0 = *(s8*)&Xs[buf][wm * 32 + fm][ko];
      s8 a1 = *(s8*)&Xs[buf][wm * 32 + 16 + fm][ko];
      #pragma unroll
      for (int g = 0; g < 4; ++g) {
        s8 b = *(s8*)&Wd[buf][wn * 64 + g * 16 + fm][ko];
        acc[0][g] = __builtin_amdgcn_mfma_f32_16x16x32_bf16(a0, b, acc[0][g], 0, 0, 0);
        acc[1][g] = __builtin_amdgcn_mfma_f32_16x16x32_bf16(a1, b, acc[1][g], 0, 0, 0);
      }
    }
    buf ^= 1;
  }

  int rq = lane >> 4;
  #pragma unroll
  for (int g = 0; g < 4; ++g) {
    int h = htile * 128 + wn * 64 + g * 16 + (lane & 15);
    float bias = db[e * H_ + h];
    #pragma unroll
    for (int f = 0; f < 2; ++f) {
      #pragma unroll
      for (int r = 0; r < 4; ++r) {
        int m = wm * 32 + f * 16 + rq * 4 + r;
        int enc = toks[m];
        if (enc < 0) continue;
        dsout[(size_t)enc * H_ + h] = (acc[f][g][r] + bias) * tws[m];
      }
    }
  }
}

// ---------------------------------------------------------------------------
// Kernel 4: combine — out[t][h] = sum_k dsout[t*4+k][h].
// ---------------------------------------------------------------------------
__global__ __launch_bounds__(256)
void combine_kernel(const float* __restrict__ dsout,
                    float* __restrict__ routed) {
  int idx = blockIdx.x * 256 + threadIdx.x;
  int t = idx >> 8;
  int h = (idx & 255) * 4;
  const float* base = dsout + (size_t)t * 4 * H_ + h;
  float4 a = *(const float4*)(base);
  float4 b = *(const float4*)(base + H_);
  float4 c = *(const float4*)(base + 2 * H_);
  float4 d = *(const float4*)(base + 3 * H_);
  float4 o;
  o.x = a.x + b.x + c.x + d.x;
  o.y = a.y + b.y + c.y + d.y;
  o.z = a.z + b.z + c.z + d.z;
  o.w = a.w + b.w + c.w + d.w;
  *(float4*)(routed + (size_t)t * H_ + h) = o;
}

// ---------------------------------------------------------------------------
// Workspace layout (bytes):
//   counts   @ 0          (256 B)
//   tok_list @ 1 MiB      (256 KiB)
//   w_list   @ 1.25 MiB   (256 KiB)
//   x_bf     @ 2 MiB      (4 MiB)
//   act      @ 8 MiB      (16 MiB)
//   wgu      @ 24 MiB     (128 MiB)  [dead after gateup]
//   dsout    @ 24 MiB     (32 MiB)   [aliases wgu — written by down]
//   wdt      @ 152 MiB    (64 MiB)
// total required: 216 MiB
// ---------------------------------------------------------------------------
extern "C" void kernel_launch(void* const* d_in, const int* in_sizes, int n_in,
                              void* d_out, int out_size, void* d_ws, size_t ws_size,
                              hipStream_t stream) {
  (void)in_sizes; (void)n_in; (void)out_size; (void)ws_size;
  const float* x    = (const float*)d_in[0];
  const float* gup  = (const float*)d_in[1];
  const float* gupb = (const float*)d_in[2];
  const float* dwn  = (const float*)d_in[3];
  const float* dwnb = (const float*)d_in[4];
  const float* rw   = (const float*)d_in[5];
  const float* rb   = (const float*)d_in[6];

  float* routed = (float*)d_out;
  float* scores = (float*)d_out + (size_t)T_ * H_;

  char* ws = (char*)d_ws;
  int*   counts   = (int*)ws;
  int*   tok_list = (int*)(ws + ((size_t)1 << 20));
  float* w_list   = (float*)(ws + ((size_t)1 << 20) + (size_t)E_ * T_ * 4);
  unsigned short* xbf = (unsigned short*)(ws + ((size_t)2 << 20));
  unsigned short* act = (unsigned short*)(ws + ((size_t)8 << 20));
  unsigned short* wgu_b = (unsigned short*)(ws + ((size_t)24 << 20));
  float*          dsout = (float*)(ws + ((size_t)24 << 20));  // alias over wgu
  unsigned short* wdt_b = (unsigned short*)(ws + ((size_t)24 << 20)
                                            + (size_t)E_ * 2 * I_ * H_ * 2);

  hipMemsetAsync(counts, 0, E_ * sizeof(int), stream);

  cast_x_kernel<<<(T_ * H_ / 8) / 256, 256, 0, stream>>>(x, xbf);
  transpose_cast<<<dim3(2 * I_ / 64, H_ / 64, E_), 256, 0, stream>>>(
      gup, wgu_b, H_, 2 * I_, 1);
  transpose_cast<<<dim3(H_ / 64, I_ / 64, E_), 256, 0, stream>>>(
      dwn, wdt_b, I_, H_, 0);
  router_kernel<<<T_, 128, 0, stream>>>(x, rw, rb, scores, counts, tok_list, w_list);
  gateup_mfma<<<dim3(16, 32, 32), 256, 0, stream>>>(xbf, wgu_b, gupb,
                                                    counts, tok_list, act);
  down_mfma<<<dim3(8, 32, 32), 256, 0, stream>>>(act, wdt_b, dwnb,
                                                 counts, tok_list, w_list, dsout);
  combine_kernel<<<(T_ * H_ / 4) / 256, 256, 0, stream>>>(dsout, routed);
}